// Round 1
// baseline (570.374 us; speedup 1.0000x reference)
//
#include <hip/hip_runtime.h>
#include <hip/hip_bf16.h>

// SimpleFuzzyAttention: B=2, S=2048, D=1024, H=16, DK=64
// Strategy: fz(s) is a univariate function (all h*3 gaussians applied to every
// score) -> tabulate g(s)=exp(fz(s)-max) in a 2048-entry LUT; attention becomes
// LUT-lerp + un-normalized softmax accumulation. All GEMMs via bf16 MFMA.

#define S_LEN 2048
#define DMODEL 1024
#define NHEAD 16
#define DKH 64
#define NLUT 2048
#define LUT_MIN (-10.0f)
#define LUT_MAX (10.0f)

typedef __attribute__((ext_vector_type(8))) short bfx8;   // 8 bf16 (4 VGPRs)
typedef __attribute__((ext_vector_type(4))) float fx4;    // MFMA C/D

__device__ __forceinline__ short f2bf(float x) {
    unsigned u = __builtin_bit_cast(unsigned, x);
    u = (u + 0x7fffu + ((u >> 16) & 1u)) >> 16;   // RNE
    return (short)u;
}

__device__ __forceinline__ void stage8_f32(const float* __restrict__ src, short* dst) {
    float4 a = *(const float4*)(src);
    float4 b = *(const float4*)(src + 4);
    bfx8 r;
    r[0] = f2bf(a.x); r[1] = f2bf(a.y); r[2] = f2bf(a.z); r[3] = f2bf(a.w);
    r[4] = f2bf(b.x); r[5] = f2bf(b.y); r[6] = f2bf(b.z); r[7] = f2bf(b.w);
    *(bfx8*)dst = r;
}

// ---------------------------------------------------------------------------
// LUT: g(x) = exp( fz(x) - max_x fz(x) ),  fz(x) = (1/3/T) * sum_i exp(-(x-c_i)^2/(2 w_i^2))
// ---------------------------------------------------------------------------
__global__ void build_lut(const float* __restrict__ centers, const float* __restrict__ widths,
                          const float* __restrict__ temp, float* __restrict__ lut) {
    __shared__ float fzb[NLUT];
    __shared__ float red[256];
    __shared__ float cs[48], ws[48];
    int tid = threadIdx.x;
    if (tid < 48) { cs[tid] = centers[tid]; ws[tid] = widths[tid]; }
    __syncthreads();
    float invT = 1.0f / temp[0];
    const float step = (LUT_MAX - LUT_MIN) / (float)(NLUT - 1);
    float lmax = -1e30f;
    for (int i = tid; i < NLUT; i += 256) {
        float s = LUT_MIN + step * (float)i;
        float fz = 0.0f;
        #pragma unroll 1
        for (int j = 0; j < 48; j++) {
            float d = s - cs[j];
            float w = ws[j];
            fz += expf(-(d * d) / (2.0f * w * w));
        }
        fz = fz * (1.0f / 3.0f) * invT;
        fzb[i] = fz;
        lmax = fmaxf(lmax, fz);
    }
    red[tid] = lmax;
    __syncthreads();
    for (int off = 128; off > 0; off >>= 1) {
        if (tid < off) red[tid] = fmaxf(red[tid], red[tid + off]);
        __syncthreads();
    }
    float m = red[0];
    for (int i = tid; i < NLUT; i += 256) lut[i] = expf(fzb[i] - m);
}

// ---------------------------------------------------------------------------
// BT-GEMM: C[m,n] = sum_k A[m,k] * W[n,k] + bias[n], 128x128 tile, BK=32.
// AF32: A is fp32 (converted to bf16 during staging); W always fp32 source.
// mode 0: store bf16 [B,H,S,DK] (Q with scale=0.125, K with scale=1)
// mode 1: store bf16 [B,H,DK,S] (V transposed)
// mode 2: store fp32 [M, N] (final output)
// ---------------------------------------------------------------------------
template <bool AF32>
__global__ __launch_bounds__(256, 2) void gemm_bt(const void* __restrict__ Ap,
        const float* __restrict__ Wp, const float* __restrict__ bias,
        short* __restrict__ obf, float* __restrict__ of32, int mode, float scale) {
    __shared__ __align__(16) short As[128 * 32];
    __shared__ __align__(16) short Bs[128 * 32];
    int tid = threadIdx.x, wave = tid >> 6, lane = tid & 63, quad = lane >> 4, l15 = lane & 15;
    int m0 = blockIdx.y * 128, n0 = blockIdx.x * 128;
    int wm = (wave >> 1) * 64, wn = (wave & 1) * 64;

    fx4 acc[4][4];
    #pragma unroll
    for (int i = 0; i < 4; i++)
        #pragma unroll
        for (int j = 0; j < 4; j++)
            #pragma unroll
            for (int r = 0; r < 4; r++) acc[i][j][r] = 0.0f;

    for (int k0 = 0; k0 < DMODEL; k0 += 32) {
        __syncthreads();
        #pragma unroll
        for (int r = 0; r < 2; r++) {
            int c = tid + 256 * r;          // 0..511  (128 rows x 4 chunks of 8)
            int row = c >> 2, cc = (c & 3) * 8;
            if (AF32)
                stage8_f32((const float*)Ap + (size_t)(m0 + row) * DMODEL + k0 + cc, &As[row * 32 + cc]);
            else
                *(int4*)(&As[row * 32 + cc]) =
                    *(const int4*)((const short*)Ap + (size_t)(m0 + row) * DMODEL + k0 + cc);
            stage8_f32(Wp + (size_t)(n0 + row) * DMODEL + k0 + cc, &Bs[row * 32 + cc]);
        }
        __syncthreads();
        bfx8 af[4], bfr[4];
        #pragma unroll
        for (int i = 0; i < 4; i++) af[i] = *(const bfx8*)(&As[(wm + i * 16 + l15) * 32 + quad * 8]);
        #pragma unroll
        for (int j = 0; j < 4; j++) bfr[j] = *(const bfx8*)(&Bs[(wn + j * 16 + l15) * 32 + quad * 8]);
        #pragma unroll
        for (int i = 0; i < 4; i++)
            #pragma unroll
            for (int j = 0; j < 4; j++)
                acc[i][j] = __builtin_amdgcn_mfma_f32_16x16x32_bf16(af[i], bfr[j], acc[i][j], 0, 0, 0);
    }

    // epilogue: C/D layout col=lane&15 (n), row=quad*4+reg (m)
    #pragma unroll
    for (int j = 0; j < 4; j++) {
        int n = n0 + wn + j * 16 + l15;
        float bv = bias[n];
        #pragma unroll
        for (int i = 0; i < 4; i++) {
            #pragma unroll
            for (int r = 0; r < 4; r++) {
                int m = m0 + wm + i * 16 + quad * 4 + r;
                float v = (acc[i][j][r] + bv) * scale;
                if (mode == 0) {
                    int b = m >> 11, s = m & 2047, h = n >> 6, dk = n & 63;
                    obf[(((size_t)(b * NHEAD + h)) * S_LEN + s) * DKH + dk] = f2bf(v);
                } else if (mode == 1) {
                    int b = m >> 11, s = m & 2047, h = n >> 6, dk = n & 63;
                    obf[(((size_t)(b * NHEAD + h)) * DKH + dk) * S_LEN + s] = f2bf(v);
                } else {
                    of32[(size_t)m * DMODEL + n] = v;
                }
            }
        }
    }
}

// ---------------------------------------------------------------------------
// Fuzzy flash attention. Q pre-scaled by 1/sqrt(DK). One block = 128 q rows of
// one (b,h); kv tiles of 64; p = LUT(s); O += P.V via MFMA (V stored transposed
// so PV is BT-form); den via per-quad shuffle reduction, kept in registers.
// ---------------------------------------------------------------------------
__global__ __launch_bounds__(256, 2) void flash_fuzzy(const short* __restrict__ Qb,
        const short* __restrict__ Kb, const short* __restrict__ VTb,
        const float* __restrict__ lutg, short* __restrict__ AO) {
    __shared__ __align__(16) short Qs[128 * 64];
    __shared__ __align__(16) short Ks[64 * 64];
    __shared__ __align__(16) short Vs[64 * 64];   // VT tile [dk][kv]
    __shared__ __align__(16) short Ps[128 * 64];
    __shared__ float lut[NLUT];

    int tid = threadIdx.x, wave = tid >> 6, lane = tid & 63, quad = lane >> 4, l15 = lane & 15;
    int q0 = blockIdx.x * 128, bh = blockIdx.y;
    const short* Qp = Qb + (size_t)bh * S_LEN * DKH;
    const short* Kp = Kb + (size_t)bh * S_LEN * DKH;
    const short* Vp = VTb + (size_t)bh * DKH * S_LEN;

    for (int i = tid; i < NLUT; i += 256) lut[i] = lutg[i];
    #pragma unroll
    for (int r = 0; r < 4; r++) {
        int c = tid + 256 * r;                         // 1024 chunks of 8 -> 128x64
        *(int4*)(&Qs[c * 8]) = *(const int4*)(Qp + (size_t)q0 * DKH + c * 8);
    }

    fx4 oacc[2][4];
    float den[2][4];
    #pragma unroll
    for (int a = 0; a < 2; a++)
        #pragma unroll
        for (int b2 = 0; b2 < 4; b2++) {
            den[a][b2] = 0.0f;
            #pragma unroll
            for (int r = 0; r < 4; r++) oacc[a][b2][r] = 0.0f;
        }

    const float invh = (float)(NLUT - 1) / (LUT_MAX - LUT_MIN);
    const float xoff = -LUT_MIN * invh;

    for (int t0 = 0; t0 < S_LEN; t0 += 64) {
        __syncthreads();
        #pragma unroll
        for (int r = 0; r < 2; r++) {
            int c = tid + 256 * r;                     // 512 chunks of 8
            *(int4*)(&Ks[c * 8]) = *(const int4*)(Kp + (size_t)t0 * DKH + c * 8);
            int row = c >> 3, cc = (c & 7) * 8;
            *(int4*)(&Vs[row * 64 + cc]) = *(const int4*)(Vp + (size_t)row * S_LEN + t0 + cc);
        }
        __syncthreads();

        // scores: S[q, kv] = sum_d Qs[q,d] * Ks[kv,d]  (Q already has 1/8 folded)
        fx4 sac[2][4];
        #pragma unroll
        for (int a = 0; a < 2; a++)
            #pragma unroll
            for (int b2 = 0; b2 < 4; b2++)
                #pragma unroll
                for (int r = 0; r < 4; r++) sac[a][b2][r] = 0.0f;
        #pragma unroll
        for (int ks = 0; ks < 2; ks++) {
            bfx8 aq[2], bk[4];
            #pragma unroll
            for (int tm = 0; tm < 2; tm++)
                aq[tm] = *(const bfx8*)(&Qs[(wave * 32 + tm * 16 + l15) * 64 + ks * 32 + quad * 8]);
            #pragma unroll
            for (int tn = 0; tn < 4; tn++)
                bk[tn] = *(const bfx8*)(&Ks[(tn * 16 + l15) * 64 + ks * 32 + quad * 8]);
            #pragma unroll
            for (int tm = 0; tm < 2; tm++)
                #pragma unroll
                for (int tn = 0; tn < 4; tn++)
                    sac[tm][tn] = __builtin_amdgcn_mfma_f32_16x16x32_bf16(aq[tm], bk[tn], sac[tm][tn], 0, 0, 0);
        }

        // p = g(s) via LUT lerp; write P (bf16) to LDS; per-quad row sums -> den
        #pragma unroll
        for (int tm = 0; tm < 2; tm++) {
            float ps[4] = {0.0f, 0.0f, 0.0f, 0.0f};
            #pragma unroll
            for (int tn = 0; tn < 4; tn++) {
                #pragma unroll
                for (int r = 0; r < 4; r++) {
                    float s = sac[tm][tn][r];
                    float x = fmaf(s, invh, xoff);
                    x = fminf(fmaxf(x, 0.0f), (float)(NLUT - 1) - 0.5f);
                    int j = (int)x;
                    float f = x - (float)j;
                    float v0 = lut[j], v1 = lut[j + 1];
                    float pv = fmaf(f, v1 - v0, v0);
                    ps[r] += pv;
                    Ps[(wave * 32 + tm * 16 + quad * 4 + r) * 64 + tn * 16 + l15] = f2bf(pv);
                }
            }
            #pragma unroll
            for (int r = 0; r < 4; r++) {
                float v = ps[r];
                v += __shfl_xor(v, 1);
                v += __shfl_xor(v, 2);
                v += __shfl_xor(v, 4);
                v += __shfl_xor(v, 8);
                den[tm][r] += v;   // all 16 lanes of the quad hold the row sum
            }
        }
        __syncthreads();

        // O[q, dk] += sum_kv P[q,kv] * VT[dk,kv]
        #pragma unroll
        for (int ks = 0; ks < 2; ks++) {
            bfx8 ap[2], bv[4];
            #pragma unroll
            for (int tm = 0; tm < 2; tm++)
                ap[tm] = *(const bfx8*)(&Ps[(wave * 32 + tm * 16 + l15) * 64 + ks * 32 + quad * 8]);
            #pragma unroll
            for (int tn = 0; tn < 4; tn++)
                bv[tn] = *(const bfx8*)(&Vs[(tn * 16 + l15) * 64 + ks * 32 + quad * 8]);
            #pragma unroll
            for (int tm = 0; tm < 2; tm++)
                #pragma unroll
                for (int tn = 0; tn < 4; tn++)
                    oacc[tm][tn] = __builtin_amdgcn_mfma_f32_16x16x32_bf16(ap[tm], bv[tn], oacc[tm][tn], 0, 0, 0);
        }
    }

    // normalize + write attended as bf16 [B, S, H*DK]
    int b = bh >> 4, h = bh & 15;
    #pragma unroll
    for (int tm = 0; tm < 2; tm++) {
        #pragma unroll
        for (int tn = 0; tn < 4; tn++) {
            #pragma unroll
            for (int r = 0; r < 4; r++) {
                int q = q0 + wave * 32 + tm * 16 + quad * 4 + r;
                int dk = tn * 16 + l15;
                float v = oacc[tm][tn][r] / den[tm][r];
                AO[((size_t)(b * S_LEN + q)) * DMODEL + h * DKH + dk] = f2bf(v);
            }
        }
    }
}

// ---------------------------------------------------------------------------
extern "C" void kernel_launch(void* const* d_in, const int* in_sizes, int n_in,
                              void* d_out, int out_size, void* d_ws, size_t ws_size,
                              hipStream_t stream) {
    const float* query   = (const float*)d_in[0];
    const float* key_in  = (const float*)d_in[1];
    const float* value   = (const float*)d_in[2];
    const float* w_q     = (const float*)d_in[3];
    const float* b_q     = (const float*)d_in[4];
    const float* w_k     = (const float*)d_in[5];
    const float* b_k     = (const float*)d_in[6];
    const float* w_v     = (const float*)d_in[7];
    const float* b_v     = (const float*)d_in[8];
    const float* w_o     = (const float*)d_in[9];
    const float* b_o     = (const float*)d_in[10];
    const float* centers = (const float*)d_in[11];
    const float* widths  = (const float*)d_in[12];
    const float* temp    = (const float*)d_in[13];

    char* p = (char*)d_ws;
    auto alloc = [&](size_t bytes) -> void* {
        void* r = (void*)p;
        p += (bytes + 255) & ~(size_t)255;
        return r;
    };
    const size_t nBHSD = (size_t)2 * NHEAD * S_LEN * DKH;    // 4.19M
    float* lut = (float*)alloc(NLUT * sizeof(float));
    short* Qb  = (short*)alloc(nBHSD * 2);
    short* Kb  = (short*)alloc(nBHSD * 2);
    short* VTb = (short*)alloc(nBHSD * 2);
    short* AO  = (short*)alloc((size_t)2 * S_LEN * DMODEL * 2);

    build_lut<<<dim3(1), dim3(256), 0, stream>>>(centers, widths, temp, lut);
    // Q projection with 1/sqrt(DK)=0.125 folded in
    gemm_bt<true><<<dim3(8, 32), dim3(256), 0, stream>>>(query,  w_q, b_q, Qb,  nullptr, 0, 0.125f);
    gemm_bt<true><<<dim3(8, 32), dim3(256), 0, stream>>>(key_in, w_k, b_k, Kb,  nullptr, 0, 1.0f);
    gemm_bt<true><<<dim3(8, 32), dim3(256), 0, stream>>>(value,  w_v, b_v, VTb, nullptr, 1, 1.0f);
    flash_fuzzy<<<dim3(16, 32), dim3(256), 0, stream>>>(Qb, Kb, VTb, lut, AO);
    gemm_bt<false><<<dim3(8, 32), dim3(256), 0, stream>>>(AO, w_o, b_o, nullptr, (float*)d_out, 2, 1.0f);
}

// Round 2
// 541.618 us; speedup vs baseline: 1.0531x; 1.0531x over previous
//
#include <hip/hip_runtime.h>
#include <hip/hip_bf16.h>

// SimpleFuzzyAttention: B=2, S=2048, D=1024, H=16, DK=64
// fz(s) is univariate -> 2048-entry LUT of g(s)=exp(fz(s)-max); attention =
// LUT-lerp + un-normalized softmax. All GEMMs via bf16 MFMA.
// R1: LDS row padding (kills 8/16-way super-bank conflicts), Q fragments
// direct from global (frees 16KB LDS -> 3 blocks/CU), den via ones-MFMA.

#define S_LEN 2048
#define DMODEL 1024
#define NHEAD 16
#define DKH 64
#define NLUT 2048
#define LUT_MIN (-10.0f)
#define LUT_MAX (10.0f)
#define FPAD 72   // flash LDS row stride (shorts): 144B = 9 superbanks, odd -> conflict-free
#define GPAD 40   // gemm LDS row stride (shorts): 80B = 5 superbanks, odd -> conflict-free

typedef __attribute__((ext_vector_type(8))) short bfx8;   // 8 bf16 (4 VGPRs)
typedef __attribute__((ext_vector_type(4))) float fx4;    // MFMA C/D

__device__ __forceinline__ short f2bf(float x) {
    unsigned u = __builtin_bit_cast(unsigned, x);
    u = (u + 0x7fffu + ((u >> 16) & 1u)) >> 16;   // RNE
    return (short)u;
}

__device__ __forceinline__ void stage8_f32(const float* __restrict__ src, short* dst) {
    float4 a = *(const float4*)(src);
    float4 b = *(const float4*)(src + 4);
    bfx8 r;
    r[0] = f2bf(a.x); r[1] = f2bf(a.y); r[2] = f2bf(a.z); r[3] = f2bf(a.w);
    r[4] = f2bf(b.x); r[5] = f2bf(b.y); r[6] = f2bf(b.z); r[7] = f2bf(b.w);
    *(bfx8*)dst = r;
}

// ---------------------------------------------------------------------------
// LUT: g(x) = exp( fz(x) - max_x fz(x) )
// ---------------------------------------------------------------------------
__global__ void build_lut(const float* __restrict__ centers, const float* __restrict__ widths,
                          const float* __restrict__ temp, float* __restrict__ lut) {
    __shared__ float fzb[NLUT];
    __shared__ float red[256];
    __shared__ float cs[48], ws[48];
    int tid = threadIdx.x;
    if (tid < 48) { cs[tid] = centers[tid]; ws[tid] = widths[tid]; }
    __syncthreads();
    float invT = 1.0f / temp[0];
    const float step = (LUT_MAX - LUT_MIN) / (float)(NLUT - 1);
    float lmax = -1e30f;
    for (int i = tid; i < NLUT; i += 256) {
        float s = LUT_MIN + step * (float)i;
        float fz = 0.0f;
        #pragma unroll 1
        for (int j = 0; j < 48; j++) {
            float d = s - cs[j];
            float w = ws[j];
            fz += expf(-(d * d) / (2.0f * w * w));
        }
        fz = fz * (1.0f / 3.0f) * invT;
        fzb[i] = fz;
        lmax = fmaxf(lmax, fz);
    }
    red[tid] = lmax;
    __syncthreads();
    for (int off = 128; off > 0; off >>= 1) {
        if (tid < off) red[tid] = fmaxf(red[tid], red[tid + off]);
        __syncthreads();
    }
    float m = red[0];
    for (int i = tid; i < NLUT; i += 256) lut[i] = expf(fzb[i] - m);
}

// ---------------------------------------------------------------------------
// BT-GEMM: C[m,n] = sum_k A[m,k] * W[n,k] + bias[n], 128x128 tile, BK=32.
// ---------------------------------------------------------------------------
template <bool AF32>
__global__ __launch_bounds__(256, 2) void gemm_bt(const void* __restrict__ Ap,
        const float* __restrict__ Wp, const float* __restrict__ bias,
        short* __restrict__ obf, float* __restrict__ of32, int mode, float scale) {
    __shared__ __align__(16) short As[128 * GPAD];
    __shared__ __align__(16) short Bs[128 * GPAD];
    int tid = threadIdx.x, wave = tid >> 6, lane = tid & 63, quad = lane >> 4, l15 = lane & 15;
    int m0 = blockIdx.y * 128, n0 = blockIdx.x * 128;
    int wm = (wave >> 1) * 64, wn = (wave & 1) * 64;

    fx4 acc[4][4];
    #pragma unroll
    for (int i = 0; i < 4; i++)
        #pragma unroll
        for (int j = 0; j < 4; j++)
            #pragma unroll
            for (int r = 0; r < 4; r++) acc[i][j][r] = 0.0f;

    for (int k0 = 0; k0 < DMODEL; k0 += 32) {
        __syncthreads();
        #pragma unroll
        for (int r = 0; r < 2; r++) {
            int c = tid + 256 * r;          // 0..511  (128 rows x 4 chunks of 8)
            int row = c >> 2, cc = (c & 3) * 8;
            if (AF32)
                stage8_f32((const float*)Ap + (size_t)(m0 + row) * DMODEL + k0 + cc, &As[row * GPAD + cc]);
            else
                *(int4*)(&As[row * GPAD + cc]) =
                    *(const int4*)((const short*)Ap + (size_t)(m0 + row) * DMODEL + k0 + cc);
            stage8_f32(Wp + (size_t)(n0 + row) * DMODEL + k0 + cc, &Bs[row * GPAD + cc]);
        }
        __syncthreads();
        bfx8 af[4], bfr[4];
        #pragma unroll
        for (int i = 0; i < 4; i++) af[i] = *(const bfx8*)(&As[(wm + i * 16 + l15) * GPAD + quad * 8]);
        #pragma unroll
        for (int j = 0; j < 4; j++) bfr[j] = *(const bfx8*)(&Bs[(wn + j * 16 + l15) * GPAD + quad * 8]);
        #pragma unroll
        for (int i = 0; i < 4; i++)
            #pragma unroll
            for (int j = 0; j < 4; j++)
                acc[i][j] = __builtin_amdgcn_mfma_f32_16x16x32_bf16(af[i], bfr[j], acc[i][j], 0, 0, 0);
    }

    // epilogue: C/D layout col=lane&15 (n), row=quad*4+reg (m)
    #pragma unroll
    for (int j = 0; j < 4; j++) {
        int n = n0 + wn + j * 16 + l15;
        float bv = bias[n];
        #pragma unroll
        for (int i = 0; i < 4; i++) {
            #pragma unroll
            for (int r = 0; r < 4; r++) {
                int m = m0 + wm + i * 16 + quad * 4 + r;
                float v = (acc[i][j][r] + bv) * scale;
                if (mode == 0) {
                    int b = m >> 11, s = m & 2047, h = n >> 6, dk = n & 63;
                    obf[(((size_t)(b * NHEAD + h)) * S_LEN + s) * DKH + dk] = f2bf(v);
                } else if (mode == 1) {
                    int b = m >> 11, s = m & 2047, h = n >> 6, dk = n & 63;
                    obf[(((size_t)(b * NHEAD + h)) * DKH + dk) * S_LEN + s] = f2bf(v);
                } else {
                    of32[(size_t)m * DMODEL + n] = v;
                }
            }
        }
    }
}

// ---------------------------------------------------------------------------
// Fuzzy flash attention. One block = 128 q rows of one (b,h); kv tiles of 64.
// Q fragments loaded once from global (A-layout is directly addressable).
// den accumulated via ones-MFMA (same layout as oacc rows).
// ---------------------------------------------------------------------------
__global__ __launch_bounds__(256, 3) void flash_fuzzy(const short* __restrict__ Qb,
        const short* __restrict__ Kb, const short* __restrict__ VTb,
        const float* __restrict__ lutg, short* __restrict__ AO) {
    __shared__ __align__(16) short Ks[64 * FPAD];
    __shared__ __align__(16) short Vs[64 * FPAD];   // VT tile [dk][kv]
    __shared__ __align__(16) short Ps[128 * FPAD];
    __shared__ float lut[NLUT];

    int tid = threadIdx.x, wave = tid >> 6, lane = tid & 63, quad = lane >> 4, l15 = lane & 15;
    int q0 = blockIdx.x * 128, bh = blockIdx.y;
    const short* Qp = Qb + (size_t)bh * S_LEN * DKH;
    const short* Kp = Kb + (size_t)bh * S_LEN * DKH;
    const short* Vp = VTb + (size_t)bh * DKH * S_LEN;

    for (int i = tid; i < NLUT; i += 256) lut[i] = lutg[i];

    // Q fragments: A-layout row = l15 (within 16-row tile), k = quad*8..+7
    bfx8 aq[2][2];   // [ks][tm]
    #pragma unroll
    for (int ks = 0; ks < 2; ks++)
        #pragma unroll
        for (int tm = 0; tm < 2; tm++)
            aq[ks][tm] = *(const bfx8*)(Qp + (size_t)(q0 + wave * 32 + tm * 16 + l15) * DKH
                                        + ks * 32 + quad * 8);

    bfx8 ones;
    #pragma unroll
    for (int i = 0; i < 8; i++) ones[i] = (short)0x3F80;  // bf16 1.0

    fx4 oacc[2][4];
    fx4 dacc[2];
    #pragma unroll
    for (int a = 0; a < 2; a++) {
        #pragma unroll
        for (int r = 0; r < 4; r++) dacc[a][r] = 0.0f;
        #pragma unroll
        for (int b2 = 0; b2 < 4; b2++)
            #pragma unroll
            for (int r = 0; r < 4; r++) oacc[a][b2][r] = 0.0f;
    }

    const float invh = (float)(NLUT - 1) / (LUT_MAX - LUT_MIN);
    const float xoff = -LUT_MIN * invh;

    for (int t0 = 0; t0 < S_LEN; t0 += 64) {
        __syncthreads();
        #pragma unroll
        for (int r = 0; r < 2; r++) {
            int c = tid + 256 * r;                     // 512 chunks of 8
            int row = c >> 3, cc = (c & 7) * 8;
            *(int4*)(&Ks[row * FPAD + cc]) = *(const int4*)(Kp + (size_t)(t0 + row) * DKH + cc);
            *(int4*)(&Vs[row * FPAD + cc]) = *(const int4*)(Vp + (size_t)row * S_LEN + t0 + cc);
        }
        __syncthreads();

        // scores: S[q, kv] = sum_d Q[q,d] * K[kv,d]  (1/8 pre-folded into Q)
        fx4 sac[2][4];
        #pragma unroll
        for (int a = 0; a < 2; a++)
            #pragma unroll
            for (int b2 = 0; b2 < 4; b2++)
                #pragma unroll
                for (int r = 0; r < 4; r++) sac[a][b2][r] = 0.0f;
        #pragma unroll
        for (int ks = 0; ks < 2; ks++) {
            bfx8 bk[4];
            #pragma unroll
            for (int tn = 0; tn < 4; tn++)
                bk[tn] = *(const bfx8*)(&Ks[(tn * 16 + l15) * FPAD + ks * 32 + quad * 8]);
            #pragma unroll
            for (int tm = 0; tm < 2; tm++)
                #pragma unroll
                for (int tn = 0; tn < 4; tn++)
                    sac[tm][tn] = __builtin_amdgcn_mfma_f32_16x16x32_bf16(aq[ks][tm], bk[tn], sac[tm][tn], 0, 0, 0);
        }

        // p = g(s) via LUT lerp; write P (bf16) to LDS in C-layout position
        #pragma unroll
        for (int tm = 0; tm < 2; tm++) {
            #pragma unroll
            for (int tn = 0; tn < 4; tn++) {
                #pragma unroll
                for (int r = 0; r < 4; r++) {
                    float s = sac[tm][tn][r];
                    float x = fmaf(s, invh, xoff);
                    x = fminf(fmaxf(x, 0.0f), (float)(NLUT - 1) - 0.5f);
                    int j = (int)x;
                    float f = x - (float)j;
                    float v0 = lut[j], v1 = lut[j + 1];
                    float pv = fmaf(f, v1 - v0, v0);
                    Ps[(wave * 32 + tm * 16 + quad * 4 + r) * FPAD + tn * 16 + l15] = f2bf(pv);
                }
            }
        }
        __syncthreads();

        // O[q, dk] += sum_kv P[q,kv] * VT[dk,kv];  den[q] += sum_kv P[q,kv]
        #pragma unroll
        for (int ks = 0; ks < 2; ks++) {
            bfx8 ap[2], bv[4];
            #pragma unroll
            for (int tm = 0; tm < 2; tm++)
                ap[tm] = *(const bfx8*)(&Ps[(wave * 32 + tm * 16 + l15) * FPAD + ks * 32 + quad * 8]);
            #pragma unroll
            for (int tn = 0; tn < 4; tn++)
                bv[tn] = *(const bfx8*)(&Vs[(tn * 16 + l15) * FPAD + ks * 32 + quad * 8]);
            #pragma unroll
            for (int tm = 0; tm < 2; tm++) {
                #pragma unroll
                for (int tn = 0; tn < 4; tn++)
                    oacc[tm][tn] = __builtin_amdgcn_mfma_f32_16x16x32_bf16(ap[tm], bv[tn], oacc[tm][tn], 0, 0, 0);
                dacc[tm] = __builtin_amdgcn_mfma_f32_16x16x32_bf16(ap[tm], ones, dacc[tm], 0, 0, 0);
            }
        }
    }

    // normalize + write attended as bf16 [B, S, H*DK]
    int b = bh >> 4, h = bh & 15;
    #pragma unroll
    for (int tm = 0; tm < 2; tm++) {
        #pragma unroll
        for (int tn = 0; tn < 4; tn++) {
            #pragma unroll
            for (int r = 0; r < 4; r++) {
                int q = q0 + wave * 32 + tm * 16 + quad * 4 + r;
                int dk = tn * 16 + l15;
                float v = oacc[tm][tn][r] / dacc[tm][r];
                AO[((size_t)(b * S_LEN + q)) * DMODEL + h * DKH + dk] = f2bf(v);
            }
        }
    }
}

// ---------------------------------------------------------------------------
extern "C" void kernel_launch(void* const* d_in, const int* in_sizes, int n_in,
                              void* d_out, int out_size, void* d_ws, size_t ws_size,
                              hipStream_t stream) {
    const float* query   = (const float*)d_in[0];
    const float* key_in  = (const float*)d_in[1];
    const float* value   = (const float*)d_in[2];
    const float* w_q     = (const float*)d_in[3];
    const float* b_q     = (const float*)d_in[4];
    const float* w_k     = (const float*)d_in[5];
    const float* b_k     = (const float*)d_in[6];
    const float* w_v     = (const float*)d_in[7];
    const float* b_v     = (const float*)d_in[8];
    const float* w_o     = (const float*)d_in[9];
    const float* b_o     = (const float*)d_in[10];
    const float* centers = (const float*)d_in[11];
    const float* widths  = (const float*)d_in[12];
    const float* temp    = (const float*)d_in[13];

    char* p = (char*)d_ws;
    auto alloc = [&](size_t bytes) -> void* {
        void* r = (void*)p;
        p += (bytes + 255) & ~(size_t)255;
        return r;
    };
    const size_t nBHSD = (size_t)2 * NHEAD * S_LEN * DKH;    // 4.19M
    float* lut = (float*)alloc(NLUT * sizeof(float));
    short* Qb  = (short*)alloc(nBHSD * 2);
    short* Kb  = (short*)alloc(nBHSD * 2);
    short* VTb = (short*)alloc(nBHSD * 2);
    short* AO  = (short*)alloc((size_t)2 * S_LEN * DMODEL * 2);

    build_lut<<<dim3(1), dim3(256), 0, stream>>>(centers, widths, temp, lut);
    // Q projection with 1/sqrt(DK)=0.125 folded in
    gemm_bt<true><<<dim3(8, 32), dim3(256), 0, stream>>>(query,  w_q, b_q, Qb,  nullptr, 0, 0.125f);
    gemm_bt<true><<<dim3(8, 32), dim3(256), 0, stream>>>(key_in, w_k, b_k, Kb,  nullptr, 0, 1.0f);
    gemm_bt<true><<<dim3(8, 32), dim3(256), 0, stream>>>(value,  w_v, b_v, VTb, nullptr, 1, 1.0f);
    flash_fuzzy<<<dim3(16, 32), dim3(256), 0, stream>>>(Qb, Kb, VTb, lut, AO);
    gemm_bt<false><<<dim3(8, 32), dim3(256), 0, stream>>>(AO, w_o, b_o, nullptr, (float*)d_out, 2, 1.0f);
}

// Round 3
// 394.869 us; speedup vs baseline: 1.4445x; 1.3716x over previous
//
#include <hip/hip_runtime.h>
#include <hip/hip_bf16.h>

// SimpleFuzzyAttention: B=2, S=2048, D=1024, H=16, DK=64
// fz(s) is univariate -> 2048-entry LUT of g(s)=exp(fz(s)-max); attention =
// LUT-lerp + un-normalized softmax. All GEMMs via bf16 MFMA.
// R2: pre-cast fp32->bf16 once; GEMMs use global_load_lds(16B) m97-style,
// 128x64 tiles, 512 blocks (2/CU). Flash: 64-row q-tiles -> 1024 blocks,
// 4 blocks/CU (16 waves) to hide lut-gather + barrier latency.

#define S_LEN 2048
#define DMODEL 1024
#define NHEAD 16
#define DKH 64
#define NLUT 2048
#define LUT_MIN (-10.0f)
#define LUT_MAX (10.0f)
#define FPAD 72   // flash LDS row stride (shorts): 144B, odd superbank count

typedef __attribute__((ext_vector_type(8))) short bfx8;   // 8 bf16 (4 VGPRs)
typedef __attribute__((ext_vector_type(4))) float fx4;    // MFMA C/D

__device__ __forceinline__ short f2bf(float x) {
    unsigned u = __builtin_bit_cast(unsigned, x);
    u = (u + 0x7fffu + ((u >> 16) & 1u)) >> 16;   // RNE
    return (short)u;
}

__device__ __forceinline__ void stage8_f32(const float* __restrict__ src, short* dst) {
    float4 a = *(const float4*)(src);
    float4 b = *(const float4*)(src + 4);
    bfx8 r;
    r[0] = f2bf(a.x); r[1] = f2bf(a.y); r[2] = f2bf(a.z); r[3] = f2bf(a.w);
    r[4] = f2bf(b.x); r[5] = f2bf(b.y); r[6] = f2bf(b.z); r[7] = f2bf(b.w);
    *(bfx8*)dst = r;
}

// global -> LDS direct 16B copy (dst must be wave-uniform base; lane*16 implied)
__device__ __forceinline__ void gload_lds16(const void* g, void* l) {
    __builtin_amdgcn_global_load_lds(
        (const __attribute__((address_space(1))) unsigned int*)g,
        (__attribute__((address_space(3))) unsigned int*)l, 16, 0, 0);
}

// ---------------------------------------------------------------------------
// fp32 -> bf16 cast, 8 elems/thread
// ---------------------------------------------------------------------------
__global__ void cast_bf16(const float* __restrict__ src, short* __restrict__ dst, int n8) {
    int i = blockIdx.x * 256 + threadIdx.x;
    if (i < n8) stage8_f32(src + (size_t)i * 8, dst + (size_t)i * 8);
}

// ---------------------------------------------------------------------------
// LUT: g(x) = exp( fz(x) - max_x fz(x) )
// ---------------------------------------------------------------------------
__global__ void build_lut(const float* __restrict__ centers, const float* __restrict__ widths,
                          const float* __restrict__ temp, float* __restrict__ lut) {
    __shared__ float fzb[NLUT];
    __shared__ float red[256];
    __shared__ float cs[48], ws[48];
    int tid = threadIdx.x;
    if (tid < 48) { cs[tid] = centers[tid]; ws[tid] = widths[tid]; }
    __syncthreads();
    float invT = 1.0f / temp[0];
    const float step = (LUT_MAX - LUT_MIN) / (float)(NLUT - 1);
    float lmax = -1e30f;
    for (int i = tid; i < NLUT; i += 256) {
        float s = LUT_MIN + step * (float)i;
        float fz = 0.0f;
        #pragma unroll 1
        for (int j = 0; j < 48; j++) {
            float d = s - cs[j];
            float w = ws[j];
            fz += expf(-(d * d) / (2.0f * w * w));
        }
        fz = fz * (1.0f / 3.0f) * invT;
        fzb[i] = fz;
        lmax = fmaxf(lmax, fz);
    }
    red[tid] = lmax;
    __syncthreads();
    for (int off = 128; off > 0; off >>= 1) {
        if (tid < off) red[tid] = fmaxf(red[tid], red[tid + off]);
        __syncthreads();
    }
    float m = red[0];
    for (int i = tid; i < NLUT; i += 256) lut[i] = expf(fzb[i] - m);
}

// ---------------------------------------------------------------------------
// bf16 BT-GEMM: C[m,n] = sum_k A[m,k]*W[n,k] + bias[n]. Tile 128x64, BK=32,
// global_load_lds staging (m97 structure). grid (N/64, M/128).
// mode 0: bf16 [B,H,S,DK]; mode 1: bf16 [B,H,DK,S] (transposed); mode 2: fp32 [M,N]
// ---------------------------------------------------------------------------
__global__ __launch_bounds__(256, 2) void gemm_bt(const short* __restrict__ A,
        const short* __restrict__ W, const float* __restrict__ bias,
        short* __restrict__ obf, float* __restrict__ of32, int mode, float scale) {
    __shared__ __align__(16) short As[128 * 32];   // 8 KB, unpadded (global_load_lds)
    __shared__ __align__(16) short Bs[64 * 32];    // 4 KB
    int tid = threadIdx.x, wave = tid >> 6, lane = tid & 63, quad = lane >> 4, l15 = lane & 15;
    int m0 = blockIdx.y * 128, n0 = blockIdx.x * 64;
    int wm = (wave >> 1) * 64, wn = (wave & 1) * 32;

    fx4 acc[4][2];
    #pragma unroll
    for (int i = 0; i < 4; i++)
        #pragma unroll
        for (int j = 0; j < 2; j++)
            #pragma unroll
            for (int r = 0; r < 4; r++) acc[i][j][r] = 0.0f;

    for (int k0 = 0; k0 < DMODEL; k0 += 32) {
        __syncthreads();
        #pragma unroll
        for (int r = 0; r < 2; r++) {
            int g = r * 256 + tid;                 // 512 chunks of 16B -> 128x32
            gload_lds16(A + (size_t)(m0 + (g >> 2)) * DMODEL + k0 + (g & 3) * 8,
                        &As[(r * 256 + wave * 64) * 8]);
        }
        {
            int g = tid;                           // 256 chunks -> 64x32
            gload_lds16(W + (size_t)(n0 + (g >> 2)) * DMODEL + k0 + (g & 3) * 8,
                        &Bs[(wave * 64) * 8]);
        }
        __syncthreads();
        bfx8 af[4], bfr[2];
        #pragma unroll
        for (int i = 0; i < 4; i++) af[i] = *(const bfx8*)(&As[(wm + i * 16 + l15) * 32 + quad * 8]);
        #pragma unroll
        for (int j = 0; j < 2; j++) bfr[j] = *(const bfx8*)(&Bs[(wn + j * 16 + l15) * 32 + quad * 8]);
        #pragma unroll
        for (int i = 0; i < 4; i++)
            #pragma unroll
            for (int j = 0; j < 2; j++)
                acc[i][j] = __builtin_amdgcn_mfma_f32_16x16x32_bf16(af[i], bfr[j], acc[i][j], 0, 0, 0);
    }

    // epilogue: C/D layout col=lane&15 (n), row=quad*4+reg (m)
    #pragma unroll
    for (int j = 0; j < 2; j++) {
        int n = n0 + wn + j * 16 + l15;
        float bv = bias[n];
        #pragma unroll
        for (int i = 0; i < 4; i++) {
            #pragma unroll
            for (int r = 0; r < 4; r++) {
                int m = m0 + wm + i * 16 + quad * 4 + r;
                float v = (acc[i][j][r] + bv) * scale;
                if (mode == 0) {
                    int b = m >> 11, s = m & 2047, h = n >> 6, dk = n & 63;
                    obf[(((size_t)(b * NHEAD + h)) * S_LEN + s) * DKH + dk] = f2bf(v);
                } else if (mode == 1) {
                    int b = m >> 11, s = m & 2047, h = n >> 6, dk = n & 63;
                    obf[(((size_t)(b * NHEAD + h)) * DKH + dk) * S_LEN + s] = f2bf(v);
                } else {
                    of32[(size_t)m * DMODEL + n] = v;
                }
            }
        }
    }
}

// ---------------------------------------------------------------------------
// Fuzzy flash attention. One block = 64 q rows of one (b,h); kv tiles of 64.
// 4 blocks/CU target. Q fragments direct from global; den via ones-MFMA.
// ---------------------------------------------------------------------------
__global__ __launch_bounds__(256, 4) void flash_fuzzy(const short* __restrict__ Qb,
        const short* __restrict__ Kb, const short* __restrict__ VTb,
        const float* __restrict__ lutg, short* __restrict__ AO) {
    __shared__ __align__(16) short Ks[64 * FPAD];
    __shared__ __align__(16) short Vs[64 * FPAD];   // VT tile [dk][kv]
    __shared__ __align__(16) short Ps[64 * FPAD];
    __shared__ float lut[NLUT];

    int tid = threadIdx.x, wave = tid >> 6, lane = tid & 63, quad = lane >> 4, l15 = lane & 15;
    int q0 = blockIdx.x * 64, bh = blockIdx.y;
    const short* Qp = Qb + (size_t)bh * S_LEN * DKH;
    const short* Kp = Kb + (size_t)bh * S_LEN * DKH;
    const short* Vp = VTb + (size_t)bh * DKH * S_LEN;

    #pragma unroll
    for (int i = tid; i < NLUT / 4; i += 256)
        ((float4*)lut)[i] = ((const float4*)lutg)[i];

    // Q fragments: A-layout row = l15 (this wave's 16-row tile), k = ks*32+quad*8..+7
    bfx8 aq[2];
    #pragma unroll
    for (int ks = 0; ks < 2; ks++)
        aq[ks] = *(const bfx8*)(Qp + (size_t)(q0 + wave * 16 + l15) * DKH + ks * 32 + quad * 8);

    bfx8 ones;
    #pragma unroll
    for (int i = 0; i < 8; i++) ones[i] = (short)0x3F80;  // bf16 1.0

    fx4 oacc[4];
    fx4 dacc;
    #pragma unroll
    for (int r = 0; r < 4; r++) dacc[r] = 0.0f;
    #pragma unroll
    for (int tn = 0; tn < 4; tn++)
        #pragma unroll
        for (int r = 0; r < 4; r++) oacc[tn][r] = 0.0f;

    const float invh = (float)(NLUT - 1) / (LUT_MAX - LUT_MIN);
    const float xoff = -LUT_MIN * invh;

    for (int t0 = 0; t0 < S_LEN; t0 += 64) {
        __syncthreads();
        #pragma unroll
        for (int r = 0; r < 2; r++) {
            int c = tid + 256 * r;                     // 512 chunks of 8
            int row = c >> 3, cc = (c & 7) * 8;
            *(int4*)(&Ks[row * FPAD + cc]) = *(const int4*)(Kp + (size_t)(t0 + row) * DKH + cc);
            *(int4*)(&Vs[row * FPAD + cc]) = *(const int4*)(Vp + (size_t)row * S_LEN + t0 + cc);
        }
        __syncthreads();

        // scores: S[q, kv] = sum_d Q[q,d] * K[kv,d]  (1/8 pre-folded into Q)
        fx4 sac[4];
        #pragma unroll
        for (int tn = 0; tn < 4; tn++)
            #pragma unroll
            for (int r = 0; r < 4; r++) sac[tn][r] = 0.0f;
        #pragma unroll
        for (int ks = 0; ks < 2; ks++) {
            bfx8 bk[4];
            #pragma unroll
            for (int tn = 0; tn < 4; tn++)
                bk[tn] = *(const bfx8*)(&Ks[(tn * 16 + l15) * FPAD + ks * 32 + quad * 8]);
            #pragma unroll
            for (int tn = 0; tn < 4; tn++)
                sac[tn] = __builtin_amdgcn_mfma_f32_16x16x32_bf16(aq[ks], bk[tn], sac[tn], 0, 0, 0);
        }

        // p = g(s) via LUT lerp; write P (bf16) to LDS in C-layout position
        #pragma unroll
        for (int tn = 0; tn < 4; tn++) {
            #pragma unroll
            for (int r = 0; r < 4; r++) {
                float s = sac[tn][r];
                float x = fmaf(s, invh, xoff);
                x = fminf(fmaxf(x, 0.0f), (float)(NLUT - 1) - 0.5f);
                int j = (int)x;
                float f = x - (float)j;
                float v0 = lut[j], v1 = lut[j + 1];
                float pv = fmaf(f, v1 - v0, v0);
                Ps[(wave * 16 + quad * 4 + r) * FPAD + tn * 16 + l15] = f2bf(pv);
            }
        }
        __syncthreads();

        // O[q, dk] += sum_kv P[q,kv] * VT[dk,kv];  den[q] += sum_kv P[q,kv]
        #pragma unroll
        for (int ks = 0; ks < 2; ks++) {
            bfx8 ap, bv[4];
            ap = *(const bfx8*)(&Ps[(wave * 16 + l15) * FPAD + ks * 32 + quad * 8]);
            #pragma unroll
            for (int tn = 0; tn < 4; tn++)
                bv[tn] = *(const bfx8*)(&Vs[(tn * 16 + l15) * FPAD + ks * 32 + quad * 8]);
            #pragma unroll
            for (int tn = 0; tn < 4; tn++)
                oacc[tn] = __builtin_amdgcn_mfma_f32_16x16x32_bf16(ap, bv[tn], oacc[tn], 0, 0, 0);
            dacc = __builtin_amdgcn_mfma_f32_16x16x32_bf16(ap, ones, dacc, 0, 0, 0);
        }
    }

    // normalize + write attended as bf16 [B, S, H*DK]
    int b = bh >> 4, h = bh & 15;
    #pragma unroll
    for (int tn = 0; tn < 4; tn++) {
        #pragma unroll
        for (int r = 0; r < 4; r++) {
            int q = q0 + wave * 16 + quad * 4 + r;
            int dk = tn * 16 + l15;
            float v = oacc[tn][r] / dacc[r];
            AO[((size_t)(b * S_LEN + q)) * DMODEL + h * DKH + dk] = f2bf(v);
        }
    }
}

// ---------------------------------------------------------------------------
extern "C" void kernel_launch(void* const* d_in, const int* in_sizes, int n_in,
                              void* d_out, int out_size, void* d_ws, size_t ws_size,
                              hipStream_t stream) {
    const float* query   = (const float*)d_in[0];
    const float* key_in  = (const float*)d_in[1];
    const float* value   = (const float*)d_in[2];
    const float* w_q     = (const float*)d_in[3];
    const float* b_q     = (const float*)d_in[4];
    const float* w_k     = (const float*)d_in[5];
    const float* b_k     = (const float*)d_in[6];
    const float* w_v     = (const float*)d_in[7];
    const float* b_v     = (const float*)d_in[8];
    const float* w_o     = (const float*)d_in[9];
    const float* b_o     = (const float*)d_in[10];
    const float* centers = (const float*)d_in[11];
    const float* widths  = (const float*)d_in[12];
    const float* temp    = (const float*)d_in[13];

    char* p = (char*)d_ws;
    auto alloc = [&](size_t bytes) -> void* {
        void* r = (void*)p;
        p += (bytes + 255) & ~(size_t)255;
        return r;
    };
    const size_t nBHSD = (size_t)2 * NHEAD * S_LEN * DKH;    // 4.19M elems
    const size_t nW    = (size_t)DMODEL * DMODEL;            // 1.05M elems
    float* lut = (float*)alloc(NLUT * sizeof(float));
    short* Qb  = (short*)alloc(nBHSD * 2);
    short* Kb  = (short*)alloc(nBHSD * 2);
    short* VTb = (short*)alloc(nBHSD * 2);
    short* xf  = (short*)alloc(nBHSD * 2);   // staging for casted q/k/v; reused as AO
    short* wb  = (short*)alloc(nW * 2);      // staging for casted weight (reused 4x)
    short* AO  = xf;                          // alias: xf dead after gemm_v

    const int n8x = (int)(nBHSD / 8);        // 524288 -> 2048 blocks
    const int n8w = (int)(nW / 8);           // 131072 -> 512 blocks
    dim3 cg((n8x + 255) / 256), cw((n8w + 255) / 256), blk(256);
    dim3 gg(16, 32);                         // gemm: N/64 x M/128

    build_lut<<<dim3(1), blk, 0, stream>>>(centers, widths, temp, lut);

    cast_bf16<<<cg, blk, 0, stream>>>(query, xf, n8x);
    cast_bf16<<<cw, blk, 0, stream>>>(w_q, wb, n8w);
    gemm_bt<<<gg, blk, 0, stream>>>(xf, wb, b_q, Qb, nullptr, 0, 0.125f);  // 1/sqrt(64) folded

    cast_bf16<<<cg, blk, 0, stream>>>(key_in, xf, n8x);
    cast_bf16<<<cw, blk, 0, stream>>>(w_k, wb, n8w);
    gemm_bt<<<gg, blk, 0, stream>>>(xf, wb, b_k, Kb, nullptr, 0, 1.0f);

    cast_bf16<<<cg, blk, 0, stream>>>(value, xf, n8x);
    cast_bf16<<<cw, blk, 0, stream>>>(w_v, wb, n8w);
    gemm_bt<<<gg, blk, 0, stream>>>(xf, wb, b_v, VTb, nullptr, 1, 1.0f);

    flash_fuzzy<<<dim3(32, 32), blk, 0, stream>>>(Qb, Kb, VTb, lut, AO);

    cast_bf16<<<cw, blk, 0, stream>>>(w_o, wb, n8w);
    gemm_bt<<<gg, blk, 0, stream>>>(AO, wb, b_o, nullptr, (float*)d_out, 2, 1.0f);
}

// Round 4
// 321.105 us; speedup vs baseline: 1.7763x; 1.2297x over previous
//
#include <hip/hip_runtime.h>
#include <hip/hip_bf16.h>

// SimpleFuzzyAttention: B=2, S=2048, D=1024, H=16, DK=64
// fz(s) is univariate -> packed-pair LUT of g(s)=exp(fz(s)-max); attention =
// 1-gather LUT lerp + un-normalized softmax. All GEMMs via bf16 MFMA.
// R3: bf16-pair LUT (1 gather/score), XOR-swizzled LDS (conflict-free frag
// reads, enables global_load_lds staging in flash), wave-private Ps (drop 3rd
// barrier), fused QKV GEMM (grid.z=3, ~6 blocks/CU), 4 launches total.

#define S_LEN 2048
#define DMODEL 1024
#define NHEAD 16
#define DKH 64
#define NLUT 2048
#define LUT_MIN (-10.0f)
#define LUT_MAX (10.0f)
#define FPAD 72   // Ps row stride (shorts): 144B, conflict-free for its patterns

typedef __attribute__((ext_vector_type(8))) short bfx8;   // 8 bf16 (4 VGPRs)
typedef __attribute__((ext_vector_type(4))) float fx4;    // MFMA C/D

__device__ __forceinline__ short f2bf(float x) {
    unsigned u = __builtin_bit_cast(unsigned, x);
    u = (u + 0x7fffu + ((u >> 16) & 1u)) >> 16;   // RNE
    return (short)u;
}

__device__ __forceinline__ void stage8_f32(const float* __restrict__ src, short* dst) {
    float4 a = *(const float4*)(src);
    float4 b = *(const float4*)(src + 4);
    bfx8 r;
    r[0] = f2bf(a.x); r[1] = f2bf(a.y); r[2] = f2bf(a.z); r[3] = f2bf(a.w);
    r[4] = f2bf(b.x); r[5] = f2bf(b.y); r[6] = f2bf(b.z); r[7] = f2bf(b.w);
    *(bfx8*)dst = r;
}

// global -> LDS direct 16B copy (LDS base wave-uniform; lane*16 implied)
__device__ __forceinline__ void gload_lds16(const void* g, void* l) {
    __builtin_amdgcn_global_load_lds(
        (const __attribute__((address_space(1))) unsigned int*)g,
        (__attribute__((address_space(3))) unsigned int*)l, 16, 0, 0);
}

// ---------------------------------------------------------------------------
// LUT body: lutp[j] = bf16(g[j]) | bf16(g[j+1])<<16, g = exp(fz - max fz)
// ---------------------------------------------------------------------------
__device__ void lut_body(const float* __restrict__ centers, const float* __restrict__ widths,
                         const float* __restrict__ temp, unsigned* __restrict__ lutp) {
    __shared__ float fzb[NLUT];
    __shared__ float red[256];
    __shared__ float cs[48], wsb[48];
    int tid = threadIdx.x;
    if (tid < 48) { cs[tid] = centers[tid]; wsb[tid] = widths[tid]; }
    __syncthreads();
    float invT = 1.0f / temp[0];
    const float step = (LUT_MAX - LUT_MIN) / (float)(NLUT - 1);
    float lmax = -1e30f;
    for (int i = tid; i < NLUT; i += 256) {
        float s = LUT_MIN + step * (float)i;
        float fz = 0.0f;
        #pragma unroll 1
        for (int j = 0; j < 48; j++) {
            float d = s - cs[j];
            float w = wsb[j];
            fz += expf(-(d * d) / (2.0f * w * w));
        }
        fz = fz * (1.0f / 3.0f) * invT;
        fzb[i] = fz;
        lmax = fmaxf(lmax, fz);
    }
    red[tid] = lmax;
    __syncthreads();
    for (int off = 128; off > 0; off >>= 1) {
        if (tid < off) red[tid] = fmaxf(red[tid], red[tid + off]);
        __syncthreads();
    }
    float m = red[0];
    __syncthreads();
    for (int i = tid; i < NLUT; i += 256) fzb[i] = expf(fzb[i] - m);
    __syncthreads();
    for (int i = tid; i < NLUT; i += 256) {
        float g0 = fzb[i];
        float g1 = fzb[(i + 1 < NLUT) ? i + 1 : NLUT - 1];
        unsigned lo = (unsigned short)f2bf(g0);
        unsigned hi = (unsigned short)f2bf(g1);
        lutp[i] = lo | (hi << 16);
    }
}

__global__ void build_lut_pk(const float* centers, const float* widths,
                             const float* temp, unsigned* lutp) {
    lut_body(centers, widths, temp, lutp);
}

// ---------------------------------------------------------------------------
// fp32 -> bf16 cast (fallback path), 8 elems/thread
// ---------------------------------------------------------------------------
__global__ void cast_bf16(const float* __restrict__ src, short* __restrict__ dst, int n8) {
    int i = blockIdx.x * 256 + threadIdx.x;
    if (i < n8) stage8_f32(src + (size_t)i * 8, dst + (size_t)i * 8);
}

// ---------------------------------------------------------------------------
// Fused prep: y=0..2 cast inputs, y=3..6 cast weights, y=7 block 0 builds LUT
// ---------------------------------------------------------------------------
__global__ void prep_all(const float* q, const float* kin, const float* v,
        const float* wq, const float* wk, const float* wv, const float* wo,
        short* xq, short* xk, short* xv,
        short* bwq, short* bwk, short* bwv, short* bwo,
        const float* centers, const float* widths, const float* temp,
        unsigned* lutp) {
    int y = blockIdx.y;
    if (y == 7) {
        if (blockIdx.x == 0) lut_body(centers, widths, temp, lutp);
        return;
    }
    const float* src; short* dst; int n8;
    switch (y) {
        case 0: src = q;   dst = xq;  n8 = (2 * S_LEN * DMODEL) / 8; break;
        case 1: src = kin; dst = xk;  n8 = (2 * S_LEN * DMODEL) / 8; break;
        case 2: src = v;   dst = xv;  n8 = (2 * S_LEN * DMODEL) / 8; break;
        case 3: src = wq;  dst = bwq; n8 = (DMODEL * DMODEL) / 8; break;
        case 4: src = wk;  dst = bwk; n8 = (DMODEL * DMODEL) / 8; break;
        case 5: src = wv;  dst = bwv; n8 = (DMODEL * DMODEL) / 8; break;
        default: src = wo; dst = bwo; n8 = (DMODEL * DMODEL) / 8; break;
    }
    int i = blockIdx.x * 256 + threadIdx.x;
    if (i < n8) stage8_f32(src + (size_t)i * 8, dst + (size_t)i * 8);
}

// ---------------------------------------------------------------------------
// bf16 BT-GEMM: C[m,n] = sum_k A[m,k]*W[n,k] + bias[n]. Tile 128x64, BK=32,
// global_load_lds staging with XOR swizzle chunk^=((row>>1)&3) -> frag reads
// are 2-way (free). grid (N/64, M/128, njobs).
// mode 0: bf16 [B,H,S,DK]; 1: bf16 [B,H,DK,S]; 2: fp32 [M,N]
// ---------------------------------------------------------------------------
struct GemmJob {
    const short* A; const short* W; const float* bias;
    short* obf; float* of32; int mode; float scale;
};

__global__ __launch_bounds__(256, 4) void gemm_mt(GemmJob j0, GemmJob j1, GemmJob j2) {
    __shared__ __align__(16) short As[128 * 32];   // 8 KB, unpadded + swizzled
    __shared__ __align__(16) short Bs[64 * 32];    // 4 KB
    GemmJob jb = (blockIdx.z == 0) ? j0 : (blockIdx.z == 1) ? j1 : j2;
    int tid = threadIdx.x, wave = tid >> 6, lane = tid & 63, quad = lane >> 4, l15 = lane & 15;
    int m0 = blockIdx.y * 128, n0 = blockIdx.x * 64;
    int wm = (wave >> 1) * 64, wn = (wave & 1) * 32;

    fx4 acc[4][2];
    #pragma unroll
    for (int i = 0; i < 4; i++)
        #pragma unroll
        for (int j = 0; j < 2; j++)
            #pragma unroll
            for (int r = 0; r < 4; r++) acc[i][j][r] = 0.0f;

    // per-lane swizzled source chunks (constant across k-loop)
    int fc = (quad ^ ((l15 >> 1) & 3)) * 8;        // fragment-read chunk offset (shorts)

    for (int k0 = 0; k0 < DMODEL; k0 += 32) {
        __syncthreads();
        #pragma unroll
        for (int r = 0; r < 2; r++) {
            int slot = r * 256 + wave * 64 + lane;
            int row = slot >> 2, c = slot & 3, gc = c ^ ((row >> 1) & 3);
            gload_lds16(jb.A + (size_t)(m0 + row) * DMODEL + k0 + gc * 8,
                        &As[(r * 256 + wave * 64) * 8]);
        }
        {
            int slot = wave * 64 + lane;
            int row = slot >> 2, c = slot & 3, gc = c ^ ((row >> 1) & 3);
            gload_lds16(jb.W + (size_t)(n0 + row) * DMODEL + k0 + gc * 8,
                        &Bs[(wave * 64) * 8]);
        }
        __syncthreads();
        bfx8 af[4], bfr[2];
        #pragma unroll
        for (int i = 0; i < 4; i++) af[i] = *(const bfx8*)(&As[(wm + i * 16 + l15) * 32 + fc]);
        #pragma unroll
        for (int j = 0; j < 2; j++) bfr[j] = *(const bfx8*)(&Bs[(wn + j * 16 + l15) * 32 + fc]);
        #pragma unroll
        for (int i = 0; i < 4; i++)
            #pragma unroll
            for (int j = 0; j < 2; j++)
                acc[i][j] = __builtin_amdgcn_mfma_f32_16x16x32_bf16(af[i], bfr[j], acc[i][j], 0, 0, 0);
    }

    // epilogue: C/D layout col=lane&15 (n), row=quad*4+reg (m)
    #pragma unroll
    for (int j = 0; j < 2; j++) {
        int n = n0 + wn + j * 16 + l15;
        float bv = jb.bias[n];
        #pragma unroll
        for (int i = 0; i < 4; i++) {
            #pragma unroll
            for (int r = 0; r < 4; r++) {
                int m = m0 + wm + i * 16 + quad * 4 + r;
                float v = (acc[i][j][r] + bv) * jb.scale;
                if (jb.mode == 0) {
                    int b = m >> 11, s = m & 2047, h = n >> 6, dk = n & 63;
                    jb.obf[(((size_t)(b * NHEAD + h)) * S_LEN + s) * DKH + dk] = f2bf(v);
                } else if (jb.mode == 1) {
                    int b = m >> 11, s = m & 2047, h = n >> 6, dk = n & 63;
                    jb.obf[(((size_t)(b * NHEAD + h)) * DKH + dk) * S_LEN + s] = f2bf(v);
                } else {
                    jb.of32[(size_t)m * DMODEL + n] = v;
                }
            }
        }
    }
}

// ---------------------------------------------------------------------------
// Fuzzy flash attention. One block = 64 q rows of one (b,h); kv tiles of 64.
// K/V staged via global_load_lds with XOR swizzle chunk^=(row&7); Ps is
// wave-private (no barrier between write and read); den via ones-MFMA;
// LUT gathers: 1 packed bf16-pair b32 per score.
// ---------------------------------------------------------------------------
__global__ __launch_bounds__(256, 4) void flash_fuzzy(const short* __restrict__ Qb,
        const short* __restrict__ Kb, const short* __restrict__ VTb,
        const unsigned* __restrict__ lutg, short* __restrict__ AO) {
    __shared__ __align__(16) short Ks[64 * 64];     // 8 KB, swizzled
    __shared__ __align__(16) short Vs[64 * 64];     // 8 KB, swizzled (VT tile [dk][kv])
    __shared__ __align__(16) short Ps[64 * FPAD];   // 9 KB, padded, wave-private rows
    __shared__ unsigned lut[NLUT];                  // 8 KB packed pairs

    int tid = threadIdx.x, wave = tid >> 6, lane = tid & 63, quad = lane >> 4, l15 = lane & 15;
    int q0 = blockIdx.x * 64, bh = blockIdx.y;
    const short* Qp = Qb + (size_t)bh * S_LEN * DKH;
    const short* Kp = Kb + (size_t)bh * S_LEN * DKH;
    const short* Vp = VTb + (size_t)bh * DKH * S_LEN;

    #pragma unroll
    for (int i = tid; i < NLUT / 4; i += 256)
        ((uint4*)lut)[i] = ((const uint4*)lutg)[i];

    // Q fragments: A-layout row = l15 (this wave's 16-row tile), k = ks*32+quad*8..+7
    bfx8 aq[2];
    #pragma unroll
    for (int ks = 0; ks < 2; ks++)
        aq[ks] = *(const bfx8*)(Qp + (size_t)(q0 + wave * 16 + l15) * DKH + ks * 32 + quad * 8);

    bfx8 ones;
    #pragma unroll
    for (int i = 0; i < 8; i++) ones[i] = (short)0x3F80;  // bf16 1.0

    fx4 oacc[4];
    fx4 dacc;
    #pragma unroll
    for (int r = 0; r < 4; r++) dacc[r] = 0.0f;
    #pragma unroll
    for (int tn = 0; tn < 4; tn++)
        #pragma unroll
        for (int r = 0; r < 4; r++) oacc[tn][r] = 0.0f;

    const float invh = (float)(NLUT - 1) / (LUT_MAX - LUT_MIN);
    const float xoff = -LUT_MIN * invh;

    // staging lane geometry (constant): 512 slots of 16B per buffer, 2 instr/wave
    int srow[2], sgc[2];
    #pragma unroll
    for (int r = 0; r < 2; r++) {
        int slot = (wave * 2 + r) * 64 + lane;
        srow[r] = slot >> 3;
        sgc[r] = (slot & 7) ^ (srow[r] & 7);
    }

    for (int t0 = 0; t0 < S_LEN; t0 += 64) {
        __syncthreads();
        #pragma unroll
        for (int r = 0; r < 2; r++) {
            gload_lds16(Kp + (size_t)(t0 + srow[r]) * DKH + sgc[r] * 8,
                        &Ks[((wave * 2 + r) * 64) * 8]);
            gload_lds16(Vp + (size_t)srow[r] * S_LEN + t0 + sgc[r] * 8,
                        &Vs[((wave * 2 + r) * 64) * 8]);
        }
        __syncthreads();

        // scores: S[q, kv] = sum_d Q[q,d] * K[kv,d]  (1/8 pre-folded into Q)
        fx4 sac[4];
        #pragma unroll
        for (int tn = 0; tn < 4; tn++)
            #pragma unroll
            for (int r = 0; r < 4; r++) sac[tn][r] = 0.0f;
        #pragma unroll
        for (int ks = 0; ks < 2; ks++) {
            int fc = ((ks * 4 + quad) ^ (l15 & 7)) * 8;
            bfx8 bk[4];
            #pragma unroll
            for (int tn = 0; tn < 4; tn++)
                bk[tn] = *(const bfx8*)(&Ks[(tn * 16 + l15) * 64 + fc]);
            #pragma unroll
            for (int tn = 0; tn < 4; tn++)
                sac[tn] = __builtin_amdgcn_mfma_f32_16x16x32_bf16(aq[ks], bk[tn], sac[tn], 0, 0, 0);
        }

        // p = g(s): one packed-pair gather + lerp; write bf16 P to wave-private Ps
        #pragma unroll
        for (int tn = 0; tn < 4; tn++) {
            #pragma unroll
            for (int r = 0; r < 4; r++) {
                float s = sac[tn][r];
                float x = fmaf(s, invh, xoff);
                x = fminf(fmaxf(x, 0.0f), (float)(NLUT - 1));
                int j = (int)x;
                float f = x - (float)j;
                unsigned pr = lut[j];
                float v0 = __builtin_bit_cast(float, pr << 16);
                float v1 = __builtin_bit_cast(float, pr & 0xffff0000u);
                float pv = fmaf(f, v1 - v0, v0);
                unsigned u = __builtin_bit_cast(unsigned, pv);
                Ps[(wave * 16 + quad * 4 + r) * FPAD + tn * 16 + l15] =
                    (short)((u + 0x8000u) >> 16);   // round-half-up bf16
            }
        }
        // NO barrier: Ps rows [wave*16, wave*16+16) are written and read by this
        // wave only; compiler-inserted lgkmcnt orders within-wave LDS accesses.

        // O[q, dk] += sum_kv P[q,kv] * VT[dk,kv];  den[q] += sum_kv P[q,kv]
        #pragma unroll
        for (int ks = 0; ks < 2; ks++) {
            int fc = ((ks * 4 + quad) ^ (l15 & 7)) * 8;
            bfx8 ap, bv[4];
            ap = *(const bfx8*)(&Ps[(wave * 16 + l15) * FPAD + ks * 32 + quad * 8]);
            #pragma unroll
            for (int tn = 0; tn < 4; tn++)
                bv[tn] = *(const bfx8*)(&Vs[(tn * 16 + l15) * 64 + fc]);
            #pragma unroll
            for (int tn = 0; tn < 4; tn++)
                oacc[tn] = __builtin_amdgcn_mfma_f32_16x16x32_bf16(ap, bv[tn], oacc[tn], 0, 0, 0);
            dacc = __builtin_amdgcn_mfma_f32_16x16x32_bf16(ap, ones, dacc, 0, 0, 0);
        }
    }

    // normalize + write attended as bf16 [B, S, H*DK]
    int b = bh >> 4, h = bh & 15;
    #pragma unroll
    for (int tn = 0; tn < 4; tn++) {
        #pragma unroll
        for (int r = 0; r < 4; r++) {
            int q = q0 + wave * 16 + quad * 4 + r;
            int dk = tn * 16 + l15;
            float v = oacc[tn][r] / dacc[r];
            AO[((size_t)(b * S_LEN + q)) * DMODEL + h * DKH + dk] = f2bf(v);
        }
    }
}

// ---------------------------------------------------------------------------
extern "C" void kernel_launch(void* const* d_in, const int* in_sizes, int n_in,
                              void* d_out, int out_size, void* d_ws, size_t ws_size,
                              hipStream_t stream) {
    const float* query   = (const float*)d_in[0];
    const float* key_in  = (const float*)d_in[1];
    const float* value   = (const float*)d_in[2];
    const float* w_q     = (const float*)d_in[3];
    const float* b_q     = (const float*)d_in[4];
    const float* w_k     = (const float*)d_in[5];
    const float* b_k     = (const float*)d_in[6];
    const float* w_v     = (const float*)d_in[7];
    const float* b_v     = (const float*)d_in[8];
    const float* w_o     = (const float*)d_in[9];
    const float* b_o     = (const float*)d_in[10];
    const float* centers = (const float*)d_in[11];
    const float* widths  = (const float*)d_in[12];
    const float* temp    = (const float*)d_in[13];

    char* p = (char*)d_ws;
    auto alloc = [&](size_t bytes) -> void* {
        void* r = (void*)p;
        p += (bytes + 255) & ~(size_t)255;
        return r;
    };
    const size_t nBHSD = (size_t)2 * NHEAD * S_LEN * DKH;    // 4.19M elems
    const size_t nW    = (size_t)DMODEL * DMODEL;            // 1.05M elems
    unsigned* lutp = (unsigned*)alloc(NLUT * 4);
    short* Qb  = (short*)alloc(nBHSD * 2);
    short* Kb  = (short*)alloc(nBHSD * 2);
    short* VTb = (short*)alloc(nBHSD * 2);

    char* save = p;
    short* xq  = (short*)alloc(nBHSD * 2);
    short* xk  = (short*)alloc(nBHSD * 2);
    short* xv  = (short*)alloc(nBHSD * 2);
    short* bwq = (short*)alloc(nW * 2);
    short* bwk = (short*)alloc(nW * 2);
    short* bwv = (short*)alloc(nW * 2);
    short* bwo = (short*)alloc(nW * 2);
    bool fused = ((size_t)(p - (char*)d_ws) <= ws_size);

    dim3 blk(256);
    dim3 gg(16, 32, 3), g1(16, 32, 1), fg(32, 32);
    GemmJob JO;

    if (fused) {
        short* AO = xq;   // alias: xq dead after QKV gemm
        prep_all<<<dim3(2048, 8), blk, 0, stream>>>(query, key_in, value, w_q, w_k, w_v, w_o,
                xq, xk, xv, bwq, bwk, bwv, bwo, centers, widths, temp, lutp);
        GemmJob JQ = {xq, bwq, b_q, Qb,  nullptr, 0, 0.125f};
        GemmJob JK = {xk, bwk, b_k, Kb,  nullptr, 0, 1.0f};
        GemmJob JV = {xv, bwv, b_v, VTb, nullptr, 1, 1.0f};
        gemm_mt<<<gg, blk, 0, stream>>>(JQ, JK, JV);
        flash_fuzzy<<<fg, blk, 0, stream>>>(Qb, Kb, VTb, lutp, AO);
        JO = {AO, bwo, b_o, nullptr, (float*)d_out, 2, 1.0f};
        gemm_mt<<<g1, blk, 0, stream>>>(JO, JO, JO);
    } else {
        // serial fallback: reuse one x-buffer + one w-buffer (~36 MB total)
        p = save;
        short* xf = (short*)alloc(nBHSD * 2);
        short* wb = (short*)alloc(nW * 2);
        short* AO = xf;
        const int n8x = (int)(nBHSD / 8), n8w = (int)(nW / 8);
        dim3 cg((n8x + 255) / 256), cw((n8w + 255) / 256);
        build_lut_pk<<<dim3(1), blk, 0, stream>>>(centers, widths, temp, lutp);
        cast_bf16<<<cg, blk, 0, stream>>>(query, xf, n8x);
        cast_bf16<<<cw, blk, 0, stream>>>(w_q, wb, n8w);
        JO = {xf, wb, b_q, Qb, nullptr, 0, 0.125f};
        gemm_mt<<<g1, blk, 0, stream>>>(JO, JO, JO);
        cast_bf16<<<cg, blk, 0, stream>>>(key_in, xf, n8x);
        cast_bf16<<<cw, blk, 0, stream>>>(w_k, wb, n8w);
        JO = {xf, wb, b_k, Kb, nullptr, 0, 1.0f};
        gemm_mt<<<g1, blk, 0, stream>>>(JO, JO, JO);
        cast_bf16<<<cg, blk, 0, stream>>>(value, xf, n8x);
        cast_bf16<<<cw, blk, 0, stream>>>(w_v, wb, n8w);
        JO = {xf, wb, b_v, VTb, nullptr, 1, 1.0f};
        gemm_mt<<<g1, blk, 0, stream>>>(JO, JO, JO);
        flash_fuzzy<<<fg, blk, 0, stream>>>(Qb, Kb, VTb, lutp, AO);
        cast_bf16<<<cw, blk, 0, stream>>>(w_o, wb, n8w);
        JO = {AO, wb, b_o, nullptr, (float*)d_out, 2, 1.0f};
        gemm_mt<<<g1, blk, 0, stream>>>(JO, JO, JO);
    }
}

// Round 5
// 315.852 us; speedup vs baseline: 1.8058x; 1.0166x over previous
//
#include <hip/hip_runtime.h>
#include <hip/hip_bf16.h>

// SimpleFuzzyAttention: B=2, S=2048, D=1024, H=16, DK=64
// fz(s) is univariate -> packed-pair bf16 LUT of g(s)=exp(fz(s)-max);
// attention = 1-gather LUT lerp + un-normalized softmax. bf16 MFMA GEMMs.
// R4: 128x128 GEMM tile (m97 structure, 16 MFMA : 8 ds_read_b128 per BK=32),
// exact-grid fused prep. Flash unchanged from R3 (LDS-pipe-bound at ~92 us).

#define S_LEN 2048
#define DMODEL 1024
#define NHEAD 16
#define DKH 64
#define NLUT 2048
#define LUT_MIN (-10.0f)
#define LUT_MAX (10.0f)
#define FPAD 72   // Ps row stride (shorts): 144B, conflict-free for its patterns

typedef __attribute__((ext_vector_type(8))) short bfx8;   // 8 bf16 (4 VGPRs)
typedef __attribute__((ext_vector_type(4))) float fx4;    // MFMA C/D

__device__ __forceinline__ short f2bf(float x) {
    unsigned u = __builtin_bit_cast(unsigned, x);
    u = (u + 0x7fffu + ((u >> 16) & 1u)) >> 16;   // RNE
    return (short)u;
}

__device__ __forceinline__ void stage8_f32(const float* __restrict__ src, short* dst) {
    float4 a = *(const float4*)(src);
    float4 b = *(const float4*)(src + 4);
    bfx8 r;
    r[0] = f2bf(a.x); r[1] = f2bf(a.y); r[2] = f2bf(a.z); r[3] = f2bf(a.w);
    r[4] = f2bf(b.x); r[5] = f2bf(b.y); r[6] = f2bf(b.z); r[7] = f2bf(b.w);
    *(bfx8*)dst = r;
}

// global -> LDS direct 16B copy (LDS base wave-uniform; lane*16 implied)
__device__ __forceinline__ void gload_lds16(const void* g, void* l) {
    __builtin_amdgcn_global_load_lds(
        (const __attribute__((address_space(1))) unsigned int*)g,
        (__attribute__((address_space(3))) unsigned int*)l, 16, 0, 0);
}

// ---------------------------------------------------------------------------
// LUT body: lutp[j] = bf16(g[j]) | bf16(g[j+1])<<16, g = exp(fz - max fz)
// ---------------------------------------------------------------------------
__device__ void lut_body(const float* __restrict__ centers, const float* __restrict__ widths,
                         const float* __restrict__ temp, unsigned* __restrict__ lutp) {
    __shared__ float fzb[NLUT];
    __shared__ float red[256];
    __shared__ float cs[48], wsb[48];
    int tid = threadIdx.x;
    if (tid < 48) { cs[tid] = centers[tid]; wsb[tid] = widths[tid]; }
    __syncthreads();
    float invT = 1.0f / temp[0];
    const float step = (LUT_MAX - LUT_MIN) / (float)(NLUT - 1);
    float lmax = -1e30f;
    for (int i = tid; i < NLUT; i += 256) {
        float s = LUT_MIN + step * (float)i;
        float fz = 0.0f;
        #pragma unroll 1
        for (int j = 0; j < 48; j++) {
            float d = s - cs[j];
            float w = wsb[j];
            fz += expf(-(d * d) / (2.0f * w * w));
        }
        fz = fz * (1.0f / 3.0f) * invT;
        fzb[i] = fz;
        lmax = fmaxf(lmax, fz);
    }
    red[tid] = lmax;
    __syncthreads();
    for (int off = 128; off > 0; off >>= 1) {
        if (tid < off) red[tid] = fmaxf(red[tid], red[tid + off]);
        __syncthreads();
    }
    float m = red[0];
    __syncthreads();
    for (int i = tid; i < NLUT; i += 256) fzb[i] = expf(fzb[i] - m);
    __syncthreads();
    for (int i = tid; i < NLUT; i += 256) {
        float g0 = fzb[i];
        float g1 = fzb[(i + 1 < NLUT) ? i + 1 : NLUT - 1];
        unsigned lo = (unsigned short)f2bf(g0);
        unsigned hi = (unsigned short)f2bf(g1);
        lutp[i] = lo | (hi << 16);
    }
}

__global__ void build_lut_pk(const float* centers, const float* widths,
                             const float* temp, unsigned* lutp) {
    lut_body(centers, widths, temp, lutp);
}

// ---------------------------------------------------------------------------
// fp32 -> bf16 cast (fallback path), 8 elems/thread
// ---------------------------------------------------------------------------
__global__ void cast_bf16(const float* __restrict__ src, short* __restrict__ dst, int n8) {
    int i = blockIdx.x * 256 + threadIdx.x;
    if (i < n8) stage8_f32(src + (size_t)i * 8, dst + (size_t)i * 8);
}

// ---------------------------------------------------------------------------
// Fused prep, exact flat grid: [0,6144) inputs, [6144,8192) weights, 8192 LUT
// ---------------------------------------------------------------------------
__global__ void prep_all(const float* q, const float* kin, const float* v,
        const float* wq, const float* wk, const float* wv, const float* wo,
        short* xq, short* xk, short* xv,
        short* bwq, short* bwk, short* bwv, short* bwo,
        const float* centers, const float* widths, const float* temp,
        unsigned* lutp) {
    int bid = blockIdx.x;
    if (bid >= 8192) {
        lut_body(centers, widths, temp, lutp);
        return;
    }
    const float* src; short* dst; int blk;
    if (bid < 6144) {
        int y = bid >> 11; blk = bid & 2047;
        src = (y == 0) ? q : (y == 1) ? kin : v;
        dst = (y == 0) ? xq : (y == 1) ? xk : xv;
    } else {
        int y = (bid - 6144) >> 9; blk = (bid - 6144) & 511;
        src = (y == 0) ? wq : (y == 1) ? wk : (y == 2) ? wv : wo;
        dst = (y == 0) ? bwq : (y == 1) ? bwk : (y == 2) ? bwv : bwo;
    }
    size_t i = (size_t)blk * 256 + threadIdx.x;   // always in range (exact grids)
    stage8_f32(src + i * 8, (short*)dst + i * 8);
}

// ---------------------------------------------------------------------------
// bf16 BT-GEMM, 128x128 tile, BK=32, m97 structure: global_load_lds(16B)
// staging with XOR swizzle, 16 MFMA : 8 ds_read_b128 per k-step.
// C[m,n] = (sum_k A[m,k]*W[n,k] + bias[n]) * scale.
// mode 0: bf16 [B,H,S,DK]; 1: bf16 [B,H,DK,S]; 2: fp32 [M,N]
// ---------------------------------------------------------------------------
struct GemmJob {
    const short* A; const short* W; const float* bias;
    short* obf; float* of32; int mode; float scale;
};

__global__ __launch_bounds__(256, 2) void gemm128(GemmJob j0, GemmJob j1, GemmJob j2) {
    __shared__ __align__(16) short As[128 * 32];   // 8 KB, unpadded + swizzled
    __shared__ __align__(16) short Bs[128 * 32];   // 8 KB
    GemmJob jb = (blockIdx.z == 0) ? j0 : (blockIdx.z == 1) ? j1 : j2;
    int tid = threadIdx.x, wave = tid >> 6, lane = tid & 63, quad = lane >> 4, l15 = lane & 15;
    int m0 = blockIdx.y * 128, n0 = blockIdx.x * 128;
    int wm = (wave >> 1) * 64, wn = (wave & 1) * 64;

    fx4 acc[4][4];
    #pragma unroll
    for (int i = 0; i < 4; i++)
        #pragma unroll
        for (int j = 0; j < 4; j++)
            #pragma unroll
            for (int r = 0; r < 4; r++) acc[i][j][r] = 0.0f;

    int fc = (quad ^ ((l15 >> 1) & 3)) * 8;        // swizzled frag chunk (shorts)

    for (int k0 = 0; k0 < DMODEL; k0 += 32) {
        __syncthreads();
        #pragma unroll
        for (int r = 0; r < 2; r++) {
            int slot = r * 256 + wave * 64 + lane;   // 512 chunks of 16B -> 128x32
            int row = slot >> 2, c = slot & 3, gc = c ^ ((row >> 1) & 3);
            gload_lds16(jb.A + (size_t)(m0 + row) * DMODEL + k0 + gc * 8,
                        &As[(r * 256 + wave * 64) * 8]);
            gload_lds16(jb.W + (size_t)(n0 + row) * DMODEL + k0 + gc * 8,
                        &Bs[(r * 256 + wave * 64) * 8]);
        }
        __syncthreads();
        bfx8 af[4], bfr[4];
        #pragma unroll
        for (int i = 0; i < 4; i++) af[i] = *(const bfx8*)(&As[(wm + i * 16 + l15) * 32 + fc]);
        #pragma unroll
        for (int j = 0; j < 4; j++) bfr[j] = *(const bfx8*)(&Bs[(wn + j * 16 + l15) * 32 + fc]);
        #pragma unroll
        for (int i = 0; i < 4; i++)
            #pragma unroll
            for (int j = 0; j < 4; j++)
                acc[i][j] = __builtin_amdgcn_mfma_f32_16x16x32_bf16(af[i], bfr[j], acc[i][j], 0, 0, 0);
    }

    // epilogue: C/D layout col=lane&15 (n), row=quad*4+reg (m)
    #pragma unroll
    for (int j = 0; j < 4; j++) {
        int n = n0 + wn + j * 16 + l15;
        float bv = jb.bias[n];
        #pragma unroll
        for (int i = 0; i < 4; i++) {
            #pragma unroll
            for (int r = 0; r < 4; r++) {
                int m = m0 + wm + i * 16 + quad * 4 + r;
                float v = (acc[i][j][r] + bv) * jb.scale;
                if (jb.mode == 0) {
                    int b = m >> 11, s = m & 2047, h = n >> 6, dk = n & 63;
                    jb.obf[(((size_t)(b * NHEAD + h)) * S_LEN + s) * DKH + dk] = f2bf(v);
                } else if (jb.mode == 1) {
                    int b = m >> 11, s = m & 2047, h = n >> 6, dk = n & 63;
                    jb.obf[(((size_t)(b * NHEAD + h)) * DKH + dk) * S_LEN + s] = f2bf(v);
                } else {
                    jb.of32[(size_t)m * DMODEL + n] = v;
                }
            }
        }
    }
}

// ---------------------------------------------------------------------------
// Fuzzy flash attention (unchanged from R3). One block = 64 q rows of one
// (b,h); kv tiles of 64; K/V via global_load_lds + XOR swizzle; wave-private
// Ps (no 3rd barrier); den via ones-MFMA; 1 packed bf16-pair gather per score.
// ---------------------------------------------------------------------------
__global__ __launch_bounds__(256, 4) void flash_fuzzy(const short* __restrict__ Qb,
        const short* __restrict__ Kb, const short* __restrict__ VTb,
        const unsigned* __restrict__ lutg, short* __restrict__ AO) {
    __shared__ __align__(16) short Ks[64 * 64];     // 8 KB, swizzled
    __shared__ __align__(16) short Vs[64 * 64];     // 8 KB, swizzled (VT tile [dk][kv])
    __shared__ __align__(16) short Ps[64 * FPAD];   // 9 KB, padded, wave-private rows
    __shared__ unsigned lut[NLUT];                  // 8 KB packed pairs

    int tid = threadIdx.x, wave = tid >> 6, lane = tid & 63, quad = lane >> 4, l15 = lane & 15;
    int q0 = blockIdx.x * 64, bh = blockIdx.y;
    const short* Qp = Qb + (size_t)bh * S_LEN * DKH;
    const short* Kp = Kb + (size_t)bh * S_LEN * DKH;
    const short* Vp = VTb + (size_t)bh * DKH * S_LEN;

    #pragma unroll
    for (int i = tid; i < NLUT / 4; i += 256)
        ((uint4*)lut)[i] = ((const uint4*)lutg)[i];

    // Q fragments: A-layout row = l15 (this wave's 16-row tile), k = ks*32+quad*8..+7
    bfx8 aq[2];
    #pragma unroll
    for (int ks = 0; ks < 2; ks++)
        aq[ks] = *(const bfx8*)(Qp + (size_t)(q0 + wave * 16 + l15) * DKH + ks * 32 + quad * 8);

    bfx8 ones;
    #pragma unroll
    for (int i = 0; i < 8; i++) ones[i] = (short)0x3F80;  // bf16 1.0

    fx4 oacc[4];
    fx4 dacc;
    #pragma unroll
    for (int r = 0; r < 4; r++) dacc[r] = 0.0f;
    #pragma unroll
    for (int tn = 0; tn < 4; tn++)
        #pragma unroll
        for (int r = 0; r < 4; r++) oacc[tn][r] = 0.0f;

    const float invh = (float)(NLUT - 1) / (LUT_MAX - LUT_MIN);
    const float xoff = -LUT_MIN * invh;

    // staging lane geometry (constant): 512 slots of 16B per buffer, 2 instr/wave
    int srow[2], sgc[2];
    #pragma unroll
    for (int r = 0; r < 2; r++) {
        int slot = (wave * 2 + r) * 64 + lane;
        srow[r] = slot >> 3;
        sgc[r] = (slot & 7) ^ (srow[r] & 7);
    }

    for (int t0 = 0; t0 < S_LEN; t0 += 64) {
        __syncthreads();
        #pragma unroll
        for (int r = 0; r < 2; r++) {
            gload_lds16(Kp + (size_t)(t0 + srow[r]) * DKH + sgc[r] * 8,
                        &Ks[((wave * 2 + r) * 64) * 8]);
            gload_lds16(Vp + (size_t)srow[r] * S_LEN + t0 + sgc[r] * 8,
                        &Vs[((wave * 2 + r) * 64) * 8]);
        }
        __syncthreads();

        // scores: S[q, kv] = sum_d Q[q,d] * K[kv,d]  (1/8 pre-folded into Q)
        fx4 sac[4];
        #pragma unroll
        for (int tn = 0; tn < 4; tn++)
            #pragma unroll
            for (int r = 0; r < 4; r++) sac[tn][r] = 0.0f;
        #pragma unroll
        for (int ks = 0; ks < 2; ks++) {
            int fc = ((ks * 4 + quad) ^ (l15 & 7)) * 8;
            bfx8 bk[4];
            #pragma unroll
            for (int tn = 0; tn < 4; tn++)
                bk[tn] = *(const bfx8*)(&Ks[(tn * 16 + l15) * 64 + fc]);
            #pragma unroll
            for (int tn = 0; tn < 4; tn++)
                sac[tn] = __builtin_amdgcn_mfma_f32_16x16x32_bf16(aq[ks], bk[tn], sac[tn], 0, 0, 0);
        }

        // p = g(s): one packed-pair gather + lerp; write bf16 P to wave-private Ps
        #pragma unroll
        for (int tn = 0; tn < 4; tn++) {
            #pragma unroll
            for (int r = 0; r < 4; r++) {
                float s = sac[tn][r];
                float x = fmaf(s, invh, xoff);
                x = fminf(fmaxf(x, 0.0f), (float)(NLUT - 1));
                int j = (int)x;
                float f = x - (float)j;
                unsigned pr = lut[j];
                float v0 = __builtin_bit_cast(float, pr << 16);
                float v1 = __builtin_bit_cast(float, pr & 0xffff0000u);
                float pv = fmaf(f, v1 - v0, v0);
                unsigned u = __builtin_bit_cast(unsigned, pv);
                Ps[(wave * 16 + quad * 4 + r) * FPAD + tn * 16 + l15] =
                    (short)((u + 0x8000u) >> 16);   // round-half-up bf16
            }
        }
        // NO barrier: Ps rows [wave*16, wave*16+16) are wave-private.

        // O[q, dk] += sum_kv P[q,kv] * VT[dk,kv];  den[q] += sum_kv P[q,kv]
        #pragma unroll
        for (int ks = 0; ks < 2; ks++) {
            int fc = ((ks * 4 + quad) ^ (l15 & 7)) * 8;
            bfx8 ap, bv[4];
            ap = *(const bfx8*)(&Ps[(wave * 16 + l15) * FPAD + ks * 32 + quad * 8]);
            #pragma unroll
            for (int tn = 0; tn < 4; tn++)
                bv[tn] = *(const bfx8*)(&Vs[(tn * 16 + l15) * 64 + fc]);
            #pragma unroll
            for (int tn = 0; tn < 4; tn++)
                oacc[tn] = __builtin_amdgcn_mfma_f32_16x16x32_bf16(ap, bv[tn], oacc[tn], 0, 0, 0);
            dacc = __builtin_amdgcn_mfma_f32_16x16x32_bf16(ap, ones, dacc, 0, 0, 0);
        }
    }

    // normalize + write attended as bf16 [B, S, H*DK]
    int b = bh >> 4, h = bh & 15;
    #pragma unroll
    for (int tn = 0; tn < 4; tn++) {
        #pragma unroll
        for (int r = 0; r < 4; r++) {
            int q = q0 + wave * 16 + quad * 4 + r;
            int dk = tn * 16 + l15;
            float v = oacc[tn][r] / dacc[r];
            AO[((size_t)(b * S_LEN + q)) * DMODEL + h * DKH + dk] = f2bf(v);
        }
    }
}

// ---------------------------------------------------------------------------
extern "C" void kernel_launch(void* const* d_in, const int* in_sizes, int n_in,
                              void* d_out, int out_size, void* d_ws, size_t ws_size,
                              hipStream_t stream) {
    const float* query   = (const float*)d_in[0];
    const float* key_in  = (const float*)d_in[1];
    const float* value   = (const float*)d_in[2];
    const float* w_q     = (const float*)d_in[3];
    const float* b_q     = (const float*)d_in[4];
    const float* w_k     = (const float*)d_in[5];
    const float* b_k     = (const float*)d_in[6];
    const float* w_v     = (const float*)d_in[7];
    const float* b_v     = (const float*)d_in[8];
    const float* w_o     = (const float*)d_in[9];
    const float* b_o     = (const float*)d_in[10];
    const float* centers = (const float*)d_in[11];
    const float* widths  = (const float*)d_in[12];
    const float* temp    = (const float*)d_in[13];

    char* p = (char*)d_ws;
    auto alloc = [&](size_t bytes) -> void* {
        void* r = (void*)p;
        p += (bytes + 255) & ~(size_t)255;
        return r;
    };
    const size_t nBHSD = (size_t)2 * NHEAD * S_LEN * DKH;    // 4.19M elems
    const size_t nW    = (size_t)DMODEL * DMODEL;            // 1.05M elems
    unsigned* lutp = (unsigned*)alloc(NLUT * 4);
    short* Qb  = (short*)alloc(nBHSD * 2);
    short* Kb  = (short*)alloc(nBHSD * 2);
    short* VTb = (short*)alloc(nBHSD * 2);

    char* save = p;
    short* xq  = (short*)alloc(nBHSD * 2);
    short* xk  = (short*)alloc(nBHSD * 2);
    short* xv  = (short*)alloc(nBHSD * 2);
    short* bwq = (short*)alloc(nW * 2);
    short* bwk = (short*)alloc(nW * 2);
    short* bwv = (short*)alloc(nW * 2);
    short* bwo = (short*)alloc(nW * 2);
    bool fused = ((size_t)(p - (char*)d_ws) <= ws_size);

    dim3 blk(256);
    dim3 gq(8, 32, 3), g1(8, 32, 1), fg(32, 32);
    GemmJob JO;

    if (fused) {
        short* AO = xq;   // alias: xq dead after QKV gemm
        prep_all<<<dim3(8193), blk, 0, stream>>>(query, key_in, value, w_q, w_k, w_v, w_o,
                xq, xk, xv, bwq, bwk, bwv, bwo, centers, widths, temp, lutp);
        GemmJob JQ = {xq, bwq, b_q, Qb,  nullptr, 0, 0.125f};   // 1/sqrt(64) folded
        GemmJob JK = {xk, bwk, b_k, Kb,  nullptr, 0, 1.0f};
        GemmJob JV = {xv, bwv, b_v, VTb, nullptr, 1, 1.0f};
        gemm128<<<gq, blk, 0, stream>>>(JQ, JK, JV);
        flash_fuzzy<<<fg, blk, 0, stream>>>(Qb, Kb, VTb, lutp, AO);
        JO = {AO, bwo, b_o, nullptr, (float*)d_out, 2, 1.0f};
        gemm128<<<g1, blk, 0, stream>>>(JO, JO, JO);
    } else {
        // serial fallback: reuse one x-buffer + one w-buffer (~36 MB total)
        p = save;
        short* xf = (short*)alloc(nBHSD * 2);
        short* wb = (short*)alloc(nW * 2);
        short* AO = xf;
        const int n8x = (int)(nBHSD / 8), n8w = (int)(nW / 8);
        dim3 cg((n8x + 255) / 256), cw((n8w + 255) / 256);
        build_lut_pk<<<dim3(1), blk, 0, stream>>>(centers, widths, temp, lutp);
        cast_bf16<<<cg, blk, 0, stream>>>(query, xf, n8x);
        cast_bf16<<<cw, blk, 0, stream>>>(w_q, wb, n8w);
        JO = {xf, wb, b_q, Qb, nullptr, 0, 0.125f};
        gemm128<<<g1, blk, 0, stream>>>(JO, JO, JO);
        cast_bf16<<<cg, blk, 0, stream>>>(key_in, xf, n8x);
        cast_bf16<<<cw, blk, 0, stream>>>(w_k, wb, n8w);
        JO = {xf, wb, b_k, Kb, nullptr, 0, 1.0f};
        gemm128<<<g1, blk, 0, stream>>>(JO, JO, JO);
        cast_bf16<<<cg, blk, 0, stream>>>(value, xf, n8x);
        cast_bf16<<<cw, blk, 0, stream>>>(w_v, wb, n8w);
        JO = {xf, wb, b_v, VTb, nullptr, 1, 1.0f};
        gemm128<<<g1, blk, 0, stream>>>(JO, JO, JO);
        flash_fuzzy<<<fg, blk, 0, stream>>>(Qb, Kb, VTb, lutp, AO);
        cast_bf16<<<cw, blk, 0, stream>>>(w_o, wb, n8w);
        JO = {AO, wb, b_o, nullptr, (float*)d_out, 2, 1.0f};
        gemm128<<<g1, blk, 0, stream>>>(JO, JO, JO);
    }
}